// Round 1
// baseline (275.738 us; speedup 1.0000x reference)
//
#include <hip/hip_runtime.h>

#define B_BATCH 128
#define N_RX 34
#define IMG 512
#define N_CAT 5

// One thread per batch element. Iterates the 34 receivers IN ORDER so that
// duplicate (y,x) coordinates resolve last-write-wins, matching the numpy
// reference's scatter semantics. Total work: 4352 point-writes -> negligible;
// the 256 MiB zero-fill (hipMemsetAsync) is the actual cost.
__global__ void Vec2Im_scatter_kernel(const float* __restrict__ x_vecs,
                                      const float* __restrict__ device_weights,
                                      const float* __restrict__ device_bias,
                                      const float* __restrict__ category_weights,
                                      const float* __restrict__ category_bias,
                                      float* __restrict__ out) {
    int b = blockIdx.x * blockDim.x + threadIdx.x;
    if (b >= B_BATCH) return;

    // x_vecs row layout: [power, x, y, cat] as 4 contiguous fp32 -> float4 load
    const float4* xv = reinterpret_cast<const float4*>(x_vecs) + (size_t)b * N_RX;
    float* plane0 = out + (size_t)b * 2 * IMG * IMG;  // processed power plane
    float* plane1 = plane0 + (size_t)IMG * IMG;       // raw power plane

    for (int r = 0; r < N_RX; ++r) {
        float4 v = xv[r];
        float raw = v.x;
        float mask = (raw != 0.0f) ? 1.0f : 0.0f;
        float p = raw * device_weights[r] + mask * device_bias[r];
        int cat = (int)v.w;  // astype(int32) == truncation; values are exact ints
        p = p * category_weights[cat] + mask * category_bias[cat];
        int xx = (int)rintf(v.y);  // coords[:,:,0] -> xx
        int yy = (int)rintf(v.z);  // coords[:,:,1] -> yy
        int off = yy * IMG + xx;
        plane0[off] = p;
        plane1[off] = raw;
    }
}

extern "C" void kernel_launch(void* const* d_in, const int* in_sizes, int n_in,
                              void* d_out, int out_size, void* d_ws, size_t ws_size,
                              hipStream_t stream) {
    const float* x_vecs           = (const float*)d_in[0];
    const float* device_weights   = (const float*)d_in[1];
    const float* device_bias      = (const float*)d_in[2];
    const float* category_weights = (const float*)d_in[3];
    const float* category_bias    = (const float*)d_in[4];
    float* out = (float*)d_out;

    // Zero the whole output (harness poisons it with 0xAA before every call).
    hipMemsetAsync(d_out, 0, (size_t)out_size * sizeof(float), stream);

    // Then scatter the 4352 points (ordered per-batch for last-write-wins).
    Vec2Im_scatter_kernel<<<1, 128, 0, stream>>>(
        x_vecs, device_weights, device_bias, category_weights, category_bias, out);
}